// Round 1
// baseline (66.101 us; speedup 1.0000x reference)
//
#include <hip/hip_runtime.h>

// Problem constants (match reference)
#define BATCH 256
#define PTS   4096
#define HH    512
#define WW    512

// One thread per (b, p) point. Skip invalid (p >= num_valid[b]); valid
// indices are in [0, 512) by construction, duplicates sum via atomicAdd.
__global__ __launch_bounds__(256) void scatter_add_kernel(
        const int* __restrict__ indices,      // [B, P, 2] int32
        const int* __restrict__ num_valid,    // [B] int32
        const float* __restrict__ feats,      // [B, P, 1] f32
        float* __restrict__ out)              // [B, H, W] f32 (pre-zeroed)
{
    int tid = blockIdx.x * blockDim.x + threadIdx.x;   // 0 .. B*P-1
    int b = tid >> 12;            // tid / PTS
    int p = tid & (PTS - 1);      // tid % PTS
    int nv = num_valid[b];        // block-uniform (each block covers one b)
    if (p < nv) {
        int2 ij = *reinterpret_cast<const int2*>(indices + 2 * (size_t)tid); // coalesced 8B
        float v = feats[tid];
        size_t off = (size_t)b * (HH * WW) + (size_t)ij.x * WW + (size_t)ij.y;
        atomicAdd(out + off, v);
    }
}

extern "C" void kernel_launch(void* const* d_in, const int* in_sizes, int n_in,
                              void* d_out, int out_size, void* d_ws, size_t ws_size,
                              hipStream_t stream) {
    const int*   indices   = (const int*)d_in[0];
    const int*   num_valid = (const int*)d_in[1];
    const float* feats     = (const float*)d_in[2];
    float*       out       = (float*)d_out;

    // Harness poisons d_out once and never re-poisons between replays:
    // we must zero every call (scatter accumulates).
    hipMemsetAsync(out, 0, (size_t)out_size * sizeof(float), stream);

    int total = BATCH * PTS;          // 1,048,576 threads
    scatter_add_kernel<<<total / 256, 256, 0, stream>>>(indices, num_valid, feats, out);
}